// Round 8
// baseline (163.583 us; speedup 1.0000x reference)
//
#include <hip/hip_runtime.h>
#include <math.h>

typedef __attribute__((ext_vector_type(2))) float f32x2;
typedef __attribute__((ext_vector_type(4))) float fx4;
typedef __attribute__((ext_vector_type(8))) short s16x8;

#define SUBK 8   // sub-buckets per node (contention splitter)

// ================= CSR build =================

__global__ void scan1_k(const int* __restrict__ cnt, int* __restrict__ bsum, int n){
  __shared__ int ws[16];
  int i = blockIdx.x*1024 + threadIdx.x;
  int v = (i < n) ? cnt[i] : 0;
  #pragma unroll
  for(int m=1;m<64;m<<=1) v += __shfl_xor(v, m);
  if((threadIdx.x & 63) == 0) ws[threadIdx.x >> 6] = v;
  __syncthreads();
  if(threadIdx.x == 0){
    int s = 0;
    #pragma unroll
    for(int w=0; w<16; w++) s += ws[w];
    bsum[blockIdx.x] = s;
  }
}

// exclusive scan of nb (<=1024) block sums, one 1024-thread block
__global__ __launch_bounds__(1024) void scan2_k(int* __restrict__ bsum, int nb,
                                                int* __restrict__ bin_ptr, int nbins, int E){
  __shared__ int sm[1024];
  int t = threadIdx.x;
  int v = (t < nb) ? bsum[t] : 0;
  sm[t] = v;
  __syncthreads();
  for(int off=1; off<1024; off<<=1){
    int tv = (t>=off)? sm[t-off] : 0;
    __syncthreads();
    sm[t] += tv;
    __syncthreads();
  }
  if(t < nb) bsum[t] = sm[t] - v;
  if(t == 0) bin_ptr[nbins] = E;
}

__global__ void scan3_k(const int* __restrict__ cnt, const int* __restrict__ bsum,
                        int* __restrict__ bin_ptr, int n){
  __shared__ int sm[1024];
  int i = blockIdx.x*1024 + threadIdx.x;
  int v = (i<n)? cnt[i] : 0;
  sm[threadIdx.x] = v;
  __syncthreads();
  for(int off=1; off<1024; off<<=1){
    int t = (threadIdx.x>=off)? sm[threadIdx.x-off] : 0;
    __syncthreads();
    sm[threadIdx.x] += t;
    __syncthreads();
  }
  if(i<n)
    bin_ptr[i] = sm[threadIdx.x] - v + bsum[blockIdx.x];
}

__global__ void fill2_k(const int* __restrict__ src, const int* __restrict__ dst,
                        const int* __restrict__ slot, const int* __restrict__ bin_ptr,
                        int* __restrict__ csr_src, int E){
  int e = blockIdx.x*blockDim.x + threadIdx.x;
  if(e < E){
    int bin = dst[e]*SUBK + (e & (SUBK-1));
    csr_src[bin_ptr[bin] + slot[e]] = src[e];
  }
}

// ================= bf16 helpers =================

__device__ __forceinline__ unsigned pack_bf2(float lo, float hi){
  unsigned ul = __float_as_uint(lo); ul += 0x7fffu + ((ul>>16)&1u);
  unsigned uh = __float_as_uint(hi); uh += 0x7fffu + ((uh>>16)&1u);
  return (uh & 0xffff0000u) | (ul >> 16);
}

// ================= fused prep: countslot(sub-bucketed) + W1/W2 -> bf16 + fold =================

__global__ __launch_bounds__(256) void prep_k(
    const int* __restrict__ dst, int* __restrict__ cnt, int* __restrict__ slot, int E, int nEB,
    const float* __restrict__ W1, unsigned short* __restrict__ W1bf,
    const float* __restrict__ W2, unsigned short* __restrict__ W2bf,
    const float* __restrict__ Wp1, const float* __restrict__ bp1,
    const float* __restrict__ Wp2, const float* __restrict__ bp2,
    float* __restrict__ wfold)
{
  int b = blockIdx.x;
  int t = threadIdx.x;
  if(b < nEB){
    int e = b*256 + t;
    if(e < E){
      int bin = dst[e]*SUBK + (e & (SUBK-1));
      slot[e] = atomicAdd(&cnt[bin], 1);
    }
    return;
  }
  int tb = b - nEB;
  if(tb < 2){
    const float4* Ws = (const float4*)((tb==0)? W1 : W2);
    uint2* Wd = (uint2*)((tb==0)? W1bf : W2bf);
    #pragma unroll
    for(int i=0;i<16;i++){
      int idx = t + i*256;            // 4096 float4 = 16384 floats
      float4 v = Ws[idx];
      uint2 o; o.x = pack_bf2(v.x, v.y); o.y = pack_bf2(v.z, v.w);
      Wd[idx] = o;
    }
    return;
  }
  // fold block
  int k = t;
  if(k < 128){
    float s = 0.f;
    for(int j=0;j<64;j++) s += Wp2[j]*Wp1[(size_t)j*128 + k];
    wfold[k] = s;
  } else if(k == 128){
    float s = bp2[0];
    for(int j=0;j<64;j++) s += Wp2[j]*bp1[j];
    wfold[128] = s;
  }
}

// ================= GEMM: MFMA bf16, split-hi/lo X =================

__global__ __launch_bounds__(256) void gemm_mfma_k(
    const float* __restrict__ X, const unsigned short* __restrict__ Wbf,
    const float* __restrict__ b, unsigned short* __restrict__ Ybf, int nrows)
{
  __shared__ uint4 Wl[128*16];   // 32KB, [row][chunk ^ (row&15)]
  int t = threadIdx.x;
  {
    const uint4* Ws = (const uint4*)Wbf;
    #pragma unroll
    for(int i=0;i<8;i++){
      int idx = t + i*256;
      int row = idx >> 4, ch = idx & 15;
      Wl[(row<<4) | (ch ^ (row & 15))] = Ws[idx];
    }
  }
  __syncthreads();

  int wv = t >> 6, lane = t & 63;
  int r = lane & 15, kb = lane >> 4;
  int row = blockIdx.x*64 + wv*16 + r;
  const float* xrow = &X[(size_t)min(row, nrows-1)*128];

  fx4 acc[8];
  #pragma unroll
  for(int c=0;c<8;c++) acc[c] = (fx4){0.f,0.f,0.f,0.f};

  #pragma unroll
  for(int kt=0;kt<4;kt++){
    int k0 = kt*32 + kb*8;
    float4 v0 = *(const float4*)&xrow[k0];
    float4 v1 = *(const float4*)&xrow[k0+4];
    float vs[8] = {v0.x,v0.y,v0.z,v0.w,v1.x,v1.y,v1.z,v1.w};
    s16x8 ahi, alo;
    #pragma unroll
    for(int j=0;j<8;j++){
      unsigned u = __float_as_uint(vs[j]);
      unsigned uh = u + 0x7fffu + ((u>>16)&1u);
      unsigned short h = (unsigned short)(uh >> 16);
      float hf = __uint_as_float(((unsigned)h)<<16);
      float lo = vs[j] - hf;
      unsigned ul = __float_as_uint(lo);
      ul += 0x7fffu + ((ul>>16)&1u);
      ahi[j] = (short)h;
      alo[j] = (short)(ul>>16);
    }
    int chunk = kt*4 + kb;
    #pragma unroll
    for(int c=0;c<8;c++){
      uint4 wb = Wl[((c*16 + r)<<4) | (chunk ^ r)];
      s16x8 bb = *(s16x8*)&wb;
      acc[c] = __builtin_amdgcn_mfma_f32_16x16x32_bf16(ahi, bb, acc[c], 0,0,0);
      acc[c] = __builtin_amdgcn_mfma_f32_16x16x32_bf16(alo, bb, acc[c], 0,0,0);
    }
  }

  int orow0 = blockIdx.x*64 + wv*16 + (lane>>4)*4;
  int colb = lane & 15;
  #pragma unroll
  for(int c=0;c<8;c++){
    int col = c*16 + colb;
    float bias = b[col];
    #pragma unroll
    for(int q=0;q<4;q++){
      int orow = orow0 + q;
      if(orow < nrows){
        unsigned u = __float_as_uint(acc[c][q] + bias);
        u += 0x7fffu + ((u>>16)&1u);
        Ybf[(size_t)orow*128 + col] = (unsigned short)(u>>16);
      }
    }
  }
}

// ================= GATv2 edge phase v4 =================

#define BFLO(u) __uint_as_float((u)<<16)
#define BFHI(u) __uint_as_float((u)&0xffff0000u)
#define DPP_ADD(v, ctrl) { int _t = __builtin_amdgcn_update_dpp(0, __float_as_int(v), ctrl, 0xF, 0xF, true); (v) += __int_as_float(_t); }

template<int FUSE>
__global__ __launch_bounds__(256) void gat_v4_k(
    const unsigned short* __restrict__ XWbf,
    const float* __restrict__ att,
    const int* __restrict__ bin_ptr, const int* __restrict__ csr_src,
    float* __restrict__ outp, const float* __restrict__ wfold, int n)
{
  int wid = threadIdx.x >> 6, lane = threadIdx.x & 63;
  int node = blockIdx.x*4 + wid;
  if(node >= n) return;
  int g = lane >> 4;
  int cg = lane & 15;
  int c8 = cg * 8;

  float4 A0 = *(const float4*)&att[c8];
  float4 A1 = *(const float4*)&att[c8+4];
  f32x2 a[4] = { {A0.x,A0.y}, {A0.z,A0.w}, {A1.x,A1.y}, {A1.z,A1.w} };

  const uint4* XW4 = (const uint4*)XWbf;     // row = 16 uint4
  uint4 du = XW4[node*16 + cg];
  f32x2 xd[4] = { {BFLO(du.x),BFHI(du.x)}, {BFLO(du.y),BFHI(du.y)},
                  {BFLO(du.z),BFHI(du.z)}, {BFLO(du.w),BFHI(du.w)} };

  int beg = bin_ptr[node*SUBK], end = bin_ptr[node*SUBK + SUBK];
  float s = 0.f;
  f32x2 acc[4] = {{0.f,0.f},{0.f,0.f},{0.f,0.f},{0.f,0.f}};

  if(end > beg){
    int sn_cur = csr_src[min(beg + g, end-1)];
    int sn_nxt = (beg+4 < end) ? csr_src[min(beg+4 + g, end-1)] : sn_cur;
    uint4 u = XW4[sn_cur*16 + cg];
    for(int i = beg; i < end; i += 4){
      uint4 u_nxt = XW4[sn_nxt*16 + cg];
      int sn_nn = (i+8 < end) ? csr_src[min(i+8 + g, end-1)] : sn_nxt;
      bool ok = (i + g) < end;

      f32x2 x0 = {BFLO(u.x), BFHI(u.x)};
      f32x2 x1 = {BFLO(u.y), BFHI(u.y)};
      f32x2 x2 = {BFLO(u.z), BFHI(u.z)};
      f32x2 x3 = {BFLO(u.w), BFHI(u.w)};
      f32x2 v0 = xd[0]+x0, v1 = xd[1]+x1, v2 = xd[2]+x2, v3 = xd[3]+x3;
      f32x2 q0 = v0*0.2f, q1 = v1*0.2f, q2 = v2*0.2f, q3 = v3*0.2f;
      f32x2 l0, l1, l2, l3;
      l0.x = fmaxf(v0.x,q0.x); l0.y = fmaxf(v0.y,q0.y);
      l1.x = fmaxf(v1.x,q1.x); l1.y = fmaxf(v1.y,q1.y);
      l2.x = fmaxf(v2.x,q2.x); l2.y = fmaxf(v2.y,q2.y);
      l3.x = fmaxf(v3.x,q3.x); l3.y = fmaxf(v3.y,q3.y);
      f32x2 p2 = l0*a[0];
      p2 += l1*a[1];
      p2 += l2*a[2];
      p2 += l3*a[3];
      float p = p2.x + p2.y;
      DPP_ADD(p, 0xB1);   // xor1
      DPP_ADD(p, 0x4E);   // xor2
      DPP_ADD(p, 0x141);  // half-mirror (8-lane head group complete)
      float ex = ok ? __expf(fminf(p, 60.f)) : 0.f;
      s += ex;
      f32x2 e2 = {ex, ex};
      acc[0] += e2*x0;
      acc[1] += e2*x1;
      acc[2] += e2*x2;
      acc[3] += e2*x3;

      u = u_nxt; sn_nxt = sn_nn;
    }
  }

  s += __shfl_xor(s,16);  s += __shfl_xor(s,32);
  #pragma unroll
  for(int j=0;j<4;j++){
    acc[j].x += __shfl_xor(acc[j].x,16); acc[j].x += __shfl_xor(acc[j].x,32);
    acc[j].y += __shfl_xor(acc[j].y,16); acc[j].y += __shfl_xor(acc[j].y,32);
  }

  float inv = (s > 0.f) ? 1.f/s : 0.f;
  f32x2 o[4];
  #pragma unroll
  for(int j=0;j<4;j++){
    o[j].x = fmaxf(acc[j].x*inv, 0.f);
    o[j].y = fmaxf(acc[j].y*inv, 0.f);
  }

  if(FUSE == 0){
    if(lane < 16){
      *(float4*)&outp[(size_t)node*128 + c8]     = make_float4(o[0].x,o[0].y,o[1].x,o[1].y);
      *(float4*)&outp[(size_t)node*128 + c8 + 4] = make_float4(o[2].x,o[2].y,o[3].x,o[3].y);
    }
  } else {
    float4 wf0 = *(const float4*)&wfold[c8];
    float4 wf1 = *(const float4*)&wfold[c8+4];
    float tt = o[0].x*wf0.x + o[0].y*wf0.y + o[1].x*wf0.z + o[1].y*wf0.w
             + o[2].x*wf1.x + o[2].y*wf1.y + o[3].x*wf1.z + o[3].y*wf1.w;
    DPP_ADD(tt, 0xB1);
    DPP_ADD(tt, 0x4E);
    DPP_ADD(tt, 0x141);
    DPP_ADD(tt, 0x140);
    if(lane == 0)
      outp[node] = 1.f/(1.f + __expf(-(tt + wfold[128])));
  }
}

// ================= launcher =================

static inline size_t alignup(size_t v){ return (v + 255) & ~(size_t)255; }

extern "C" void kernel_launch(void* const* d_in, const int* in_sizes, int n_in,
                              void* d_out, int out_size, void* d_ws, size_t ws_size,
                              hipStream_t stream) {
  const float* x    = (const float*)d_in[0];
  const int*   ei   = (const int*)  d_in[1];
  const float* W1   = (const float*)d_in[2];
  const float* b1   = (const float*)d_in[3];
  const float* att1 = (const float*)d_in[4];
  const float* W2   = (const float*)d_in[5];
  const float* b2   = (const float*)d_in[6];
  const float* att2 = (const float*)d_in[7];
  const float* Wp1  = (const float*)d_in[8];
  const float* bp1  = (const float*)d_in[9];
  const float* Wp2  = (const float*)d_in[10];
  const float* bp2  = (const float*)d_in[11];
  float* out = (float*)d_out;

  int N = in_sizes[0] / 128;
  int E = in_sizes[1] / 2;
  int nbins = N * SUBK;

  char* ws = (char*)d_ws;
  size_t off = 0;
  float* G1            = (float*)(ws + off); off = alignup(off + (size_t)N*128*sizeof(float));
  unsigned short* XWbf = (unsigned short*)(ws + off); off = alignup(off + (size_t)N*128*sizeof(unsigned short));
  int* csr_src  = (int*)(ws + off); off = alignup(off + (size_t)E*sizeof(int));
  int* slot     = (int*)(ws + off); off = alignup(off + (size_t)E*sizeof(int));
  int* bin_ptr  = (int*)(ws + off); off = alignup(off + (size_t)(nbins+1)*sizeof(int));
  int* cnt      = (int*)(ws + off); off = alignup(off + (size_t)nbins*sizeof(int));
  int* bsum     = (int*)(ws + off); off = alignup(off + 1024*sizeof(int));
  unsigned short* W1bf = (unsigned short*)(ws + off); off = alignup(off + 128*128*sizeof(unsigned short));
  unsigned short* W2bf = (unsigned short*)(ws + off); off = alignup(off + 128*128*sizeof(unsigned short));
  float* wfold  = (float*)(ws + off); off = alignup(off + 129*sizeof(float));

  const int* esrc = ei;
  const int* edst = ei + E;

  hipMemsetAsync(cnt, 0, (size_t)nbins*sizeof(int), stream);

  int nEB = (E + 255) / 256;
  int nb = (nbins + 1023) / 1024;
  prep_k<<<nEB + 3, 256, 0, stream>>>(edst, cnt, slot, E, nEB,
                                      W1, W1bf, W2, W2bf, Wp1, bp1, Wp2, bp2, wfold);
  scan1_k<<<nb, 1024, 0, stream>>>(cnt, bsum, nbins);
  scan2_k<<<1, 1024, 0, stream>>>(bsum, nb, bin_ptr, nbins, E);
  scan3_k<<<nb, 1024, 0, stream>>>(cnt, bsum, bin_ptr, nbins);
  fill2_k<<<(E+255)/256, 256, 0, stream>>>(esrc, edst, slot, bin_ptr, csr_src, E);

  int gb = (N + 63) / 64;
  // layer 1
  gemm_mfma_k<<<gb, 256, 0, stream>>>(x, W1bf, b1, XWbf, N);
  gat_v4_k<0><<<(N+3)/4, 256, 0, stream>>>(XWbf, att1, bin_ptr, csr_src, G1, nullptr, N);
  // layer 2
  gemm_mfma_k<<<gb, 256, 0, stream>>>(G1, W2bf, b2, XWbf, N);
  gat_v4_k<1><<<(N+3)/4, 256, 0, stream>>>(XWbf, att2, bin_ptr, csr_src, out, wfold, N);
}

// Round 9
// 162.684 us; speedup vs baseline: 1.0055x; 1.0055x over previous
//
#include <hip/hip_runtime.h>
#include <math.h>

typedef __attribute__((ext_vector_type(2))) float f32x2;
typedef __attribute__((ext_vector_type(4))) float fx4;
typedef __attribute__((ext_vector_type(8))) short s16x8;

#define SUBK 8   // sub-buckets per node (contention splitter)

// ================= zero fill (replaces hipMemsetAsync's slow fixed-grid fill) =================

__global__ void zero_k(int4* __restrict__ p, int n4){
  int i = blockIdx.x*blockDim.x + threadIdx.x;
  if(i < n4) p[i] = make_int4(0,0,0,0);
}

// ================= CSR build =================

__global__ void scan1_k(const int* __restrict__ cnt, int* __restrict__ bsum, int n){
  __shared__ int ws[16];
  int i = blockIdx.x*1024 + threadIdx.x;
  int v = (i < n) ? cnt[i] : 0;
  #pragma unroll
  for(int m=1;m<64;m<<=1) v += __shfl_xor(v, m);
  if((threadIdx.x & 63) == 0) ws[threadIdx.x >> 6] = v;
  __syncthreads();
  if(threadIdx.x == 0){
    int s = 0;
    #pragma unroll
    for(int w=0; w<16; w++) s += ws[w];
    bsum[blockIdx.x] = s;
  }
}

// exclusive scan of nb (<=1024) block sums, one 1024-thread block
__global__ __launch_bounds__(1024) void scan2_k(int* __restrict__ bsum, int nb,
                                                int* __restrict__ bin_ptr, int nbins, int E){
  __shared__ int sm[1024];
  int t = threadIdx.x;
  int v = (t < nb) ? bsum[t] : 0;
  sm[t] = v;
  __syncthreads();
  for(int off=1; off<1024; off<<=1){
    int tv = (t>=off)? sm[t-off] : 0;
    __syncthreads();
    sm[t] += tv;
    __syncthreads();
  }
  if(t < nb) bsum[t] = sm[t] - v;
  if(t == 0) bin_ptr[nbins] = E;
}

__global__ void scan3_k(const int* __restrict__ cnt, const int* __restrict__ bsum,
                        int* __restrict__ bin_ptr, int n){
  __shared__ int sm[1024];
  int i = blockIdx.x*1024 + threadIdx.x;
  int v = (i<n)? cnt[i] : 0;
  sm[threadIdx.x] = v;
  __syncthreads();
  for(int off=1; off<1024; off<<=1){
    int t = (threadIdx.x>=off)? sm[threadIdx.x-off] : 0;
    __syncthreads();
    sm[threadIdx.x] += t;
    __syncthreads();
  }
  if(i<n)
    bin_ptr[i] = sm[threadIdx.x] - v + bsum[blockIdx.x];
}

__global__ void fill2_k(const int* __restrict__ src, const int* __restrict__ dst,
                        const int* __restrict__ slot, const int* __restrict__ bin_ptr,
                        int* __restrict__ csr_src, int E){
  int e = blockIdx.x*blockDim.x + threadIdx.x;
  if(e < E){
    int bin = dst[e]*SUBK + (e & (SUBK-1));
    csr_src[bin_ptr[bin] + slot[e]] = src[e];
  }
}

// ================= bf16 helpers =================

__device__ __forceinline__ unsigned pack_bf2(float lo, float hi){
  unsigned ul = __float_as_uint(lo); ul += 0x7fffu + ((ul>>16)&1u);
  unsigned uh = __float_as_uint(hi); uh += 0x7fffu + ((uh>>16)&1u);
  return (uh & 0xffff0000u) | (ul >> 16);
}

// ================= fused prep: countslot(sub-bucketed) + W1/W2 -> bf16 + fold =================

__global__ __launch_bounds__(256) void prep_k(
    const int* __restrict__ dst, int* __restrict__ cnt, int* __restrict__ slot, int E, int nEB,
    const float* __restrict__ W1, unsigned short* __restrict__ W1bf,
    const float* __restrict__ W2, unsigned short* __restrict__ W2bf,
    const float* __restrict__ Wp1, const float* __restrict__ bp1,
    const float* __restrict__ Wp2, const float* __restrict__ bp2,
    float* __restrict__ wfold)
{
  int b = blockIdx.x;
  int t = threadIdx.x;
  if(b < nEB){
    int e = b*256 + t;
    if(e < E){
      int bin = dst[e]*SUBK + (e & (SUBK-1));
      slot[e] = atomicAdd(&cnt[bin], 1);
    }
    return;
  }
  int tb = b - nEB;
  if(tb < 2){
    const float4* Ws = (const float4*)((tb==0)? W1 : W2);
    uint2* Wd = (uint2*)((tb==0)? W1bf : W2bf);
    #pragma unroll
    for(int i=0;i<16;i++){
      int idx = t + i*256;            // 4096 float4 = 16384 floats
      float4 v = Ws[idx];
      uint2 o; o.x = pack_bf2(v.x, v.y); o.y = pack_bf2(v.z, v.w);
      Wd[idx] = o;
    }
    return;
  }
  // fold block
  int k = t;
  if(k < 128){
    float s = 0.f;
    for(int j=0;j<64;j++) s += Wp2[j]*Wp1[(size_t)j*128 + k];
    wfold[k] = s;
  } else if(k == 128){
    float s = bp2[0];
    for(int j=0;j<64;j++) s += Wp2[j]*bp1[j];
    wfold[128] = s;
  }
}

// ================= GEMM: MFMA bf16, split-hi/lo X =================

__global__ __launch_bounds__(256) void gemm_mfma_k(
    const float* __restrict__ X, const unsigned short* __restrict__ Wbf,
    const float* __restrict__ b, unsigned short* __restrict__ Ybf, int nrows)
{
  __shared__ uint4 Wl[128*16];   // 32KB, [row][chunk ^ (row&15)]
  int t = threadIdx.x;
  {
    const uint4* Ws = (const uint4*)Wbf;
    #pragma unroll
    for(int i=0;i<8;i++){
      int idx = t + i*256;
      int row = idx >> 4, ch = idx & 15;
      Wl[(row<<4) | (ch ^ (row & 15))] = Ws[idx];
    }
  }
  __syncthreads();

  int wv = t >> 6, lane = t & 63;
  int r = lane & 15, kb = lane >> 4;
  int row = blockIdx.x*64 + wv*16 + r;
  const float* xrow = &X[(size_t)min(row, nrows-1)*128];

  fx4 acc[8];
  #pragma unroll
  for(int c=0;c<8;c++) acc[c] = (fx4){0.f,0.f,0.f,0.f};

  #pragma unroll
  for(int kt=0;kt<4;kt++){
    int k0 = kt*32 + kb*8;
    float4 v0 = *(const float4*)&xrow[k0];
    float4 v1 = *(const float4*)&xrow[k0+4];
    float vs[8] = {v0.x,v0.y,v0.z,v0.w,v1.x,v1.y,v1.z,v1.w};
    s16x8 ahi, alo;
    #pragma unroll
    for(int j=0;j<8;j++){
      unsigned u = __float_as_uint(vs[j]);
      unsigned uh = u + 0x7fffu + ((u>>16)&1u);
      unsigned short h = (unsigned short)(uh >> 16);
      float hf = __uint_as_float(((unsigned)h)<<16);
      float lo = vs[j] - hf;
      unsigned ul = __float_as_uint(lo);
      ul += 0x7fffu + ((ul>>16)&1u);
      ahi[j] = (short)h;
      alo[j] = (short)(ul>>16);
    }
    int chunk = kt*4 + kb;
    #pragma unroll
    for(int c=0;c<8;c++){
      uint4 wb = Wl[((c*16 + r)<<4) | (chunk ^ r)];
      s16x8 bb = *(s16x8*)&wb;
      acc[c] = __builtin_amdgcn_mfma_f32_16x16x32_bf16(ahi, bb, acc[c], 0,0,0);
      acc[c] = __builtin_amdgcn_mfma_f32_16x16x32_bf16(alo, bb, acc[c], 0,0,0);
    }
  }

  int orow0 = blockIdx.x*64 + wv*16 + (lane>>4)*4;
  int colb = lane & 15;
  #pragma unroll
  for(int c=0;c<8;c++){
    int col = c*16 + colb;
    float bias = b[col];
    #pragma unroll
    for(int q=0;q<4;q++){
      int orow = orow0 + q;
      if(orow < nrows){
        unsigned u = __float_as_uint(acc[c][q] + bias);
        u += 0x7fffu + ((u>>16)&1u);
        Ybf[(size_t)orow*128 + col] = (unsigned short)(u>>16);
      }
    }
  }
}

// ================= GATv2 edge phase v4 =================

#define BFLO(u) __uint_as_float((u)<<16)
#define BFHI(u) __uint_as_float((u)&0xffff0000u)
#define DPP_ADD(v, ctrl) { int _t = __builtin_amdgcn_update_dpp(0, __float_as_int(v), ctrl, 0xF, 0xF, true); (v) += __int_as_float(_t); }

template<int FUSE>
__global__ __launch_bounds__(256) void gat_v4_k(
    const unsigned short* __restrict__ XWbf,
    const float* __restrict__ att,
    const int* __restrict__ bin_ptr, const int* __restrict__ csr_src,
    float* __restrict__ outp, const float* __restrict__ wfold, int n)
{
  int wid = threadIdx.x >> 6, lane = threadIdx.x & 63;
  int node = blockIdx.x*4 + wid;
  if(node >= n) return;
  int g = lane >> 4;
  int cg = lane & 15;
  int c8 = cg * 8;

  float4 A0 = *(const float4*)&att[c8];
  float4 A1 = *(const float4*)&att[c8+4];
  f32x2 a[4] = { {A0.x,A0.y}, {A0.z,A0.w}, {A1.x,A1.y}, {A1.z,A1.w} };

  const uint4* XW4 = (const uint4*)XWbf;     // row = 16 uint4
  uint4 du = XW4[node*16 + cg];
  f32x2 xd[4] = { {BFLO(du.x),BFHI(du.x)}, {BFLO(du.y),BFHI(du.y)},
                  {BFLO(du.z),BFHI(du.z)}, {BFLO(du.w),BFHI(du.w)} };

  int beg = bin_ptr[node*SUBK], end = bin_ptr[node*SUBK + SUBK];
  float s = 0.f;
  f32x2 acc[4] = {{0.f,0.f},{0.f,0.f},{0.f,0.f},{0.f,0.f}};

  if(end > beg){
    int sn_cur = csr_src[min(beg + g, end-1)];
    int sn_nxt = (beg+4 < end) ? csr_src[min(beg+4 + g, end-1)] : sn_cur;
    uint4 u = XW4[sn_cur*16 + cg];
    for(int i = beg; i < end; i += 4){
      uint4 u_nxt = XW4[sn_nxt*16 + cg];
      int sn_nn = (i+8 < end) ? csr_src[min(i+8 + g, end-1)] : sn_nxt;
      bool ok = (i + g) < end;

      f32x2 x0 = {BFLO(u.x), BFHI(u.x)};
      f32x2 x1 = {BFLO(u.y), BFHI(u.y)};
      f32x2 x2 = {BFLO(u.z), BFHI(u.z)};
      f32x2 x3 = {BFLO(u.w), BFHI(u.w)};
      f32x2 v0 = xd[0]+x0, v1 = xd[1]+x1, v2 = xd[2]+x2, v3 = xd[3]+x3;
      f32x2 q0 = v0*0.2f, q1 = v1*0.2f, q2 = v2*0.2f, q3 = v3*0.2f;
      f32x2 l0, l1, l2, l3;
      l0.x = fmaxf(v0.x,q0.x); l0.y = fmaxf(v0.y,q0.y);
      l1.x = fmaxf(v1.x,q1.x); l1.y = fmaxf(v1.y,q1.y);
      l2.x = fmaxf(v2.x,q2.x); l2.y = fmaxf(v2.y,q2.y);
      l3.x = fmaxf(v3.x,q3.x); l3.y = fmaxf(v3.y,q3.y);
      f32x2 p2 = l0*a[0];
      p2 += l1*a[1];
      p2 += l2*a[2];
      p2 += l3*a[3];
      float p = p2.x + p2.y;
      DPP_ADD(p, 0xB1);   // xor1
      DPP_ADD(p, 0x4E);   // xor2
      DPP_ADD(p, 0x141);  // half-mirror (8-lane head group complete)
      float ex = ok ? __expf(fminf(p, 60.f)) : 0.f;
      s += ex;
      f32x2 e2 = {ex, ex};
      acc[0] += e2*x0;
      acc[1] += e2*x1;
      acc[2] += e2*x2;
      acc[3] += e2*x3;

      u = u_nxt; sn_nxt = sn_nn;
    }
  }

  s += __shfl_xor(s,16);  s += __shfl_xor(s,32);
  #pragma unroll
  for(int j=0;j<4;j++){
    acc[j].x += __shfl_xor(acc[j].x,16); acc[j].x += __shfl_xor(acc[j].x,32);
    acc[j].y += __shfl_xor(acc[j].y,16); acc[j].y += __shfl_xor(acc[j].y,32);
  }

  float inv = (s > 0.f) ? 1.f/s : 0.f;
  f32x2 o[4];
  #pragma unroll
  for(int j=0;j<4;j++){
    o[j].x = fmaxf(acc[j].x*inv, 0.f);
    o[j].y = fmaxf(acc[j].y*inv, 0.f);
  }

  if(FUSE == 0){
    if(lane < 16){
      *(float4*)&outp[(size_t)node*128 + c8]     = make_float4(o[0].x,o[0].y,o[1].x,o[1].y);
      *(float4*)&outp[(size_t)node*128 + c8 + 4] = make_float4(o[2].x,o[2].y,o[3].x,o[3].y);
    }
  } else {
    float4 wf0 = *(const float4*)&wfold[c8];
    float4 wf1 = *(const float4*)&wfold[c8+4];
    float tt = o[0].x*wf0.x + o[0].y*wf0.y + o[1].x*wf0.z + o[1].y*wf0.w
             + o[2].x*wf1.x + o[2].y*wf1.y + o[3].x*wf1.z + o[3].y*wf1.w;
    DPP_ADD(tt, 0xB1);
    DPP_ADD(tt, 0x4E);
    DPP_ADD(tt, 0x141);
    DPP_ADD(tt, 0x140);
    if(lane == 0)
      outp[node] = 1.f/(1.f + __expf(-(tt + wfold[128])));
  }
}

// ================= launcher =================

static inline size_t alignup(size_t v){ return (v + 255) & ~(size_t)255; }

extern "C" void kernel_launch(void* const* d_in, const int* in_sizes, int n_in,
                              void* d_out, int out_size, void* d_ws, size_t ws_size,
                              hipStream_t stream) {
  const float* x    = (const float*)d_in[0];
  const int*   ei   = (const int*)  d_in[1];
  const float* W1   = (const float*)d_in[2];
  const float* b1   = (const float*)d_in[3];
  const float* att1 = (const float*)d_in[4];
  const float* W2   = (const float*)d_in[5];
  const float* b2   = (const float*)d_in[6];
  const float* att2 = (const float*)d_in[7];
  const float* Wp1  = (const float*)d_in[8];
  const float* bp1  = (const float*)d_in[9];
  const float* Wp2  = (const float*)d_in[10];
  const float* bp2  = (const float*)d_in[11];
  float* out = (float*)d_out;

  int N = in_sizes[0] / 128;
  int E = in_sizes[1] / 2;
  int nbins = N * SUBK;

  char* ws = (char*)d_ws;
  size_t off = 0;
  float* G1            = (float*)(ws + off); off = alignup(off + (size_t)N*128*sizeof(float));
  unsigned short* XWbf = (unsigned short*)(ws + off); off = alignup(off + (size_t)N*128*sizeof(unsigned short));
  int* csr_src  = (int*)(ws + off); off = alignup(off + (size_t)E*sizeof(int));
  int* slot     = (int*)(ws + off); off = alignup(off + (size_t)E*sizeof(int));
  int* bin_ptr  = (int*)(ws + off); off = alignup(off + (size_t)(nbins+1)*sizeof(int));
  int* cnt      = (int*)(ws + off); off = alignup(off + (size_t)(nbins+4)*sizeof(int));
  int* bsum     = (int*)(ws + off); off = alignup(off + 1024*sizeof(int));
  unsigned short* W1bf = (unsigned short*)(ws + off); off = alignup(off + 128*128*sizeof(unsigned short));
  unsigned short* W2bf = (unsigned short*)(ws + off); off = alignup(off + 128*128*sizeof(unsigned short));
  float* wfold  = (float*)(ws + off); off = alignup(off + 129*sizeof(float));

  const int* esrc = ei;
  const int* edst = ei + E;

  // zero cnt with our own kernel: hipMemsetAsync's fillBuffer dispatch ran at a
  // fixed ~42us regardless of size (tiny fixed grid); this runs in ~2us.
  int n4 = (nbins + 3) / 4;
  zero_k<<<(n4 + 255)/256, 256, 0, stream>>>((int4*)cnt, n4);

  int nEB = (E + 255) / 256;
  int nb = (nbins + 1023) / 1024;
  prep_k<<<nEB + 3, 256, 0, stream>>>(edst, cnt, slot, E, nEB,
                                      W1, W1bf, W2, W2bf, Wp1, bp1, Wp2, bp2, wfold);
  scan1_k<<<nb, 1024, 0, stream>>>(cnt, bsum, nbins);
  scan2_k<<<1, 1024, 0, stream>>>(bsum, nb, bin_ptr, nbins, E);
  scan3_k<<<nb, 1024, 0, stream>>>(cnt, bsum, bin_ptr, nbins);
  fill2_k<<<(E+255)/256, 256, 0, stream>>>(esrc, edst, slot, bin_ptr, csr_src, E);

  int gb = (N + 63) / 64;
  // layer 1
  gemm_mfma_k<<<gb, 256, 0, stream>>>(x, W1bf, b1, XWbf, N);
  gat_v4_k<0><<<(N+3)/4, 256, 0, stream>>>(XWbf, att1, bin_ptr, csr_src, G1, nullptr, N);
  // layer 2
  gemm_mfma_k<<<gb, 256, 0, stream>>>(G1, W2bf, b2, XWbf, N);
  gat_v4_k<1><<<(N+3)/4, 256, 0, stream>>>(XWbf, att2, bin_ptr, csr_src, out, wfold, N);
}

// Round 10
// 155.614 us; speedup vs baseline: 1.0512x; 1.0454x over previous
//
#include <hip/hip_runtime.h>
#include <math.h>

typedef __attribute__((ext_vector_type(2))) float f32x2;
typedef __attribute__((ext_vector_type(4))) float fx4;
typedef __attribute__((ext_vector_type(8))) short s16x8;

#define SUBK 8   // sub-buckets per node (contention splitter)

// ================= zero fill =================

__global__ void zero_k(int4* __restrict__ p, int n4){
  int i = blockIdx.x*blockDim.x + threadIdx.x;
  if(i < n4) p[i] = make_int4(0,0,0,0);
}

// ================= CSR build =================

__global__ void scan1_k(const int* __restrict__ cnt, int* __restrict__ bsum, int n){
  __shared__ int ws[16];
  int i = blockIdx.x*1024 + threadIdx.x;
  int v = (i < n) ? cnt[i] : 0;
  #pragma unroll
  for(int m=1;m<64;m<<=1) v += __shfl_xor(v, m);
  if((threadIdx.x & 63) == 0) ws[threadIdx.x >> 6] = v;
  __syncthreads();
  if(threadIdx.x == 0){
    int s = 0;
    #pragma unroll
    for(int w=0; w<16; w++) s += ws[w];
    bsum[blockIdx.x] = s;
  }
}

__global__ __launch_bounds__(1024) void scan2_k(int* __restrict__ bsum, int nb,
                                                int* __restrict__ bin_ptr, int nbins, int E){
  __shared__ int sm[1024];
  int t = threadIdx.x;
  int v = (t < nb) ? bsum[t] : 0;
  sm[t] = v;
  __syncthreads();
  for(int off=1; off<1024; off<<=1){
    int tv = (t>=off)? sm[t-off] : 0;
    __syncthreads();
    sm[t] += tv;
    __syncthreads();
  }
  if(t < nb) bsum[t] = sm[t] - v;
  if(t == 0) bin_ptr[nbins] = E;
}

__global__ void scan3_k(const int* __restrict__ cnt, const int* __restrict__ bsum,
                        int* __restrict__ bin_ptr, int n){
  __shared__ int sm[1024];
  int i = blockIdx.x*1024 + threadIdx.x;
  int v = (i<n)? cnt[i] : 0;
  sm[threadIdx.x] = v;
  __syncthreads();
  for(int off=1; off<1024; off<<=1){
    int t = (threadIdx.x>=off)? sm[threadIdx.x-off] : 0;
    __syncthreads();
    sm[threadIdx.x] += t;
    __syncthreads();
  }
  if(i<n)
    bin_ptr[i] = sm[threadIdx.x] - v + bsum[blockIdx.x];
}

__global__ void fill2_k(const int* __restrict__ src, const int* __restrict__ dst,
                        const int* __restrict__ slot, const int* __restrict__ bin_ptr,
                        int* __restrict__ csr_src, int E){
  int e = blockIdx.x*blockDim.x + threadIdx.x;
  if(e < E){
    int bin = dst[e]*SUBK + (e & (SUBK-1));
    csr_src[bin_ptr[bin] + slot[e]] = src[e];
  }
}

// ================= bf16 helpers =================

__device__ __forceinline__ unsigned pack_bf2(float lo, float hi){
  unsigned ul = __float_as_uint(lo); ul += 0x7fffu + ((ul>>16)&1u);
  unsigned uh = __float_as_uint(hi); uh += 0x7fffu + ((uh>>16)&1u);
  return (uh & 0xffff0000u) | (ul >> 16);
}

// ================= fused prep =================

__global__ __launch_bounds__(256) void prep_k(
    const int* __restrict__ dst, int* __restrict__ cnt, int* __restrict__ slot, int E, int nEB,
    const float* __restrict__ W1, unsigned short* __restrict__ W1bf,
    const float* __restrict__ W2, unsigned short* __restrict__ W2bf,
    const float* __restrict__ Wp1, const float* __restrict__ bp1,
    const float* __restrict__ Wp2, const float* __restrict__ bp2,
    float* __restrict__ wfold)
{
  int b = blockIdx.x;
  int t = threadIdx.x;
  if(b < nEB){
    int e = b*256 + t;
    if(e < E){
      int bin = dst[e]*SUBK + (e & (SUBK-1));
      slot[e] = atomicAdd(&cnt[bin], 1);
    }
    return;
  }
  int tb = b - nEB;
  if(tb < 2){
    const float4* Ws = (const float4*)((tb==0)? W1 : W2);
    uint2* Wd = (uint2*)((tb==0)? W1bf : W2bf);
    #pragma unroll
    for(int i=0;i<16;i++){
      int idx = t + i*256;
      float4 v = Ws[idx];
      uint2 o; o.x = pack_bf2(v.x, v.y); o.y = pack_bf2(v.z, v.w);
      Wd[idx] = o;
    }
    return;
  }
  int k = t;
  if(k < 128){
    float s = 0.f;
    for(int j=0;j<64;j++) s += Wp2[j]*Wp1[(size_t)j*128 + k];
    wfold[k] = s;
  } else if(k == 128){
    float s = bp2[0];
    for(int j=0;j<64;j++) s += Wp2[j]*bp1[j];
    wfold[128] = s;
  }
}

// ================= GEMM: MFMA bf16, split-hi/lo X, LDS-coalesced epilogue =================

__global__ __launch_bounds__(256) void gemm_mfma_k(
    const float* __restrict__ X, const unsigned short* __restrict__ Wbf,
    const float* __restrict__ b, unsigned short* __restrict__ Ybf, int nrows)
{
  __shared__ uint4 Wl[128*16];   // 32KB, [row][chunk ^ (row&15)]; reused by epilogue
  int t = threadIdx.x;
  {
    const uint4* Ws = (const uint4*)Wbf;
    #pragma unroll
    for(int i=0;i<8;i++){
      int idx = t + i*256;
      int row = idx >> 4, ch = idx & 15;
      Wl[(row<<4) | (ch ^ (row & 15))] = Ws[idx];
    }
  }
  __syncthreads();

  int wv = t >> 6, lane = t & 63;
  int r = lane & 15, kb = lane >> 4;
  int row = blockIdx.x*64 + wv*16 + r;
  const float* xrow = &X[(size_t)min(row, nrows-1)*128];

  fx4 acc[8];
  #pragma unroll
  for(int c=0;c<8;c++) acc[c] = (fx4){0.f,0.f,0.f,0.f};

  #pragma unroll
  for(int kt=0;kt<4;kt++){
    int k0 = kt*32 + kb*8;
    float4 v0 = *(const float4*)&xrow[k0];
    float4 v1 = *(const float4*)&xrow[k0+4];
    float vs[8] = {v0.x,v0.y,v0.z,v0.w,v1.x,v1.y,v1.z,v1.w};
    s16x8 ahi, alo;
    #pragma unroll
    for(int j=0;j<8;j++){
      unsigned u = __float_as_uint(vs[j]);
      unsigned uh = u + 0x7fffu + ((u>>16)&1u);
      unsigned short h = (unsigned short)(uh >> 16);
      float hf = __uint_as_float(((unsigned)h)<<16);
      float lo = vs[j] - hf;
      unsigned ul = __float_as_uint(lo);
      ul += 0x7fffu + ((ul>>16)&1u);
      ahi[j] = (short)h;
      alo[j] = (short)(ul>>16);
    }
    int chunk = kt*4 + kb;
    #pragma unroll
    for(int c=0;c<8;c++){
      uint4 wb = Wl[((c*16 + r)<<4) | (chunk ^ r)];
      s16x8 bb = *(s16x8*)&wb;
      acc[c] = __builtin_amdgcn_mfma_f32_16x16x32_bf16(ahi, bb, acc[c], 0,0,0);
      acc[c] = __builtin_amdgcn_mfma_f32_16x16x32_bf16(alo, bb, acc[c], 0,0,0);
    }
  }

  // ---- epilogue: LDS transpose -> coalesced uint4 stores ----
  __syncthreads();                 // all waves done reading W from Wl
  unsigned short* lds = (unsigned short*)Wl;
  unsigned short* my = lds + wv*2048;     // 16 rows x 128 cols bf16 per wave
  int colb = lane & 15;
  int rq0 = (lane>>4)*4;
  #pragma unroll
  for(int c=0;c<8;c++){
    int col = c*16 + colb;
    float bias = b[col];
    #pragma unroll
    for(int q=0;q<4;q++){
      unsigned u = __float_as_uint(acc[c][q] + bias);
      u += 0x7fffu + ((u>>16)&1u);
      my[(rq0+q)*128 + col] = (unsigned short)(u>>16);
    }
  }
  // same-wave LDS dependency: compiler inserts lgkmcnt wait
  const uint4* my4 = (const uint4*)my;
  uint4* Y4 = (uint4*)Ybf;
  #pragma unroll
  for(int rr=0;rr<4;rr++){
    int idx = lane + 64*rr;         // 0..255 (16 rows x 16 uint4)
    int lrow = idx >> 4, lcol = idx & 15;
    int grow = blockIdx.x*64 + wv*16 + lrow;
    if(grow < nrows)
      Y4[(size_t)grow*16 + lcol] = my4[idx];
  }
}

// ================= GATv2 edge phase v5: 8 edges/iter, 2 row-gathers in flight =================

#define BFLO(u) __uint_as_float((u)<<16)
#define BFHI(u) __uint_as_float((u)&0xffff0000u)
#define DPP_ADD(v, ctrl) { int _t = __builtin_amdgcn_update_dpp(0, __float_as_int(v), ctrl, 0xF, 0xF, true); (v) += __int_as_float(_t); }

#define GAT_BODY(U, OK) { \
  f32x2 x0 = {BFLO(U.x), BFHI(U.x)}; \
  f32x2 x1 = {BFLO(U.y), BFHI(U.y)}; \
  f32x2 x2 = {BFLO(U.z), BFHI(U.z)}; \
  f32x2 x3 = {BFLO(U.w), BFHI(U.w)}; \
  f32x2 v0 = xd[0]+x0, v1 = xd[1]+x1, v2 = xd[2]+x2, v3 = xd[3]+x3; \
  f32x2 q0 = v0*0.2f, q1 = v1*0.2f, q2 = v2*0.2f, q3 = v3*0.2f; \
  f32x2 l0, l1, l2, l3; \
  l0.x = fmaxf(v0.x,q0.x); l0.y = fmaxf(v0.y,q0.y); \
  l1.x = fmaxf(v1.x,q1.x); l1.y = fmaxf(v1.y,q1.y); \
  l2.x = fmaxf(v2.x,q2.x); l2.y = fmaxf(v2.y,q2.y); \
  l3.x = fmaxf(v3.x,q3.x); l3.y = fmaxf(v3.y,q3.y); \
  f32x2 p2 = l0*a[0]; p2 += l1*a[1]; p2 += l2*a[2]; p2 += l3*a[3]; \
  float p = p2.x + p2.y; \
  DPP_ADD(p, 0xB1); \
  DPP_ADD(p, 0x4E); \
  DPP_ADD(p, 0x141); \
  float ex = (OK) ? __expf(fminf(p, 60.f)) : 0.f; \
  s += ex; \
  f32x2 e2 = {ex, ex}; \
  acc[0] += e2*x0; acc[1] += e2*x1; acc[2] += e2*x2; acc[3] += e2*x3; }

template<int FUSE>
__global__ __launch_bounds__(256) void gat_v5_k(
    const unsigned short* __restrict__ XWbf,
    const float* __restrict__ att,
    const int* __restrict__ bin_ptr, const int* __restrict__ csr_src,
    float* __restrict__ outp, const float* __restrict__ wfold, int n)
{
  int wid = threadIdx.x >> 6, lane = threadIdx.x & 63;
  int node = blockIdx.x*4 + wid;
  if(node >= n) return;
  int g = lane >> 4;
  int cg = lane & 15;
  int c8 = cg * 8;

  float4 A0 = *(const float4*)&att[c8];
  float4 A1 = *(const float4*)&att[c8+4];
  f32x2 a[4] = { {A0.x,A0.y}, {A0.z,A0.w}, {A1.x,A1.y}, {A1.z,A1.w} };

  const uint4* XW4 = (const uint4*)XWbf;     // row = 16 uint4
  uint4 du = XW4[(size_t)node*16 + cg];
  f32x2 xd[4] = { {BFLO(du.x),BFHI(du.x)}, {BFLO(du.y),BFHI(du.y)},
                  {BFLO(du.z),BFHI(du.z)}, {BFLO(du.w),BFHI(du.w)} };

  int beg = bin_ptr[node*SUBK], end = bin_ptr[node*SUBK + SUBK];
  float s = 0.f;
  f32x2 acc[4] = {{0.f,0.f},{0.f,0.f},{0.f,0.f},{0.f,0.f}};

  if(end > beg){
    // rows for iteration 0 (edges i+g and i+4+g)
    int sA = csr_src[min(beg + g,     end-1)];
    int sB = csr_src[min(beg + 4 + g, end-1)];
    uint4 uA = XW4[(size_t)sA*16 + cg];
    uint4 uB = XW4[(size_t)sB*16 + cg];
    // indices for iteration 1
    int tA = (beg+8  < end) ? csr_src[min(beg+8+g,  end-1)] : sA;
    int tB = (beg+12 < end) ? csr_src[min(beg+12+g, end-1)] : sB;
    for(int i = beg; i < end; i += 8){
      // prefetch next iteration's rows (2 gathers in flight during compute)
      uint4 pA = XW4[(size_t)tA*16 + cg];
      uint4 pB = XW4[(size_t)tB*16 + cg];
      // indices two iterations ahead
      int qA = (i+16 < end) ? csr_src[min(i+16+g, end-1)] : tA;
      int qB = (i+20 < end) ? csr_src[min(i+20+g, end-1)] : tB;
      bool okA = (i + g)     < end;
      bool okB = (i + 4 + g) < end;
      GAT_BODY(uA, okA);
      GAT_BODY(uB, okB);
      uA = pA; uB = pB; tA = qA; tB = qB;
    }
  }

  s += __shfl_xor(s,16);  s += __shfl_xor(s,32);
  #pragma unroll
  for(int j=0;j<4;j++){
    acc[j].x += __shfl_xor(acc[j].x,16); acc[j].x += __shfl_xor(acc[j].x,32);
    acc[j].y += __shfl_xor(acc[j].y,16); acc[j].y += __shfl_xor(acc[j].y,32);
  }

  float inv = (s > 0.f) ? 1.f/s : 0.f;
  f32x2 o[4];
  #pragma unroll
  for(int j=0;j<4;j++){
    o[j].x = fmaxf(acc[j].x*inv, 0.f);
    o[j].y = fmaxf(acc[j].y*inv, 0.f);
  }

  if(FUSE == 0){
    if(lane < 16){
      *(float4*)&outp[(size_t)node*128 + c8]     = make_float4(o[0].x,o[0].y,o[1].x,o[1].y);
      *(float4*)&outp[(size_t)node*128 + c8 + 4] = make_float4(o[2].x,o[2].y,o[3].x,o[3].y);
    }
  } else {
    float4 wf0 = *(const float4*)&wfold[c8];
    float4 wf1 = *(const float4*)&wfold[c8+4];
    float tt = o[0].x*wf0.x + o[0].y*wf0.y + o[1].x*wf0.z + o[1].y*wf0.w
             + o[2].x*wf1.x + o[2].y*wf1.y + o[3].x*wf1.z + o[3].y*wf1.w;
    DPP_ADD(tt, 0xB1);
    DPP_ADD(tt, 0x4E);
    DPP_ADD(tt, 0x141);
    DPP_ADD(tt, 0x140);
    if(lane == 0)
      outp[node] = 1.f/(1.f + __expf(-(tt + wfold[128])));
  }
}

// ================= launcher =================

static inline size_t alignup(size_t v){ return (v + 255) & ~(size_t)255; }

extern "C" void kernel_launch(void* const* d_in, const int* in_sizes, int n_in,
                              void* d_out, int out_size, void* d_ws, size_t ws_size,
                              hipStream_t stream) {
  const float* x    = (const float*)d_in[0];
  const int*   ei   = (const int*)  d_in[1];
  const float* W1   = (const float*)d_in[2];
  const float* b1   = (const float*)d_in[3];
  const float* att1 = (const float*)d_in[4];
  const float* W2   = (const float*)d_in[5];
  const float* b2   = (const float*)d_in[6];
  const float* att2 = (const float*)d_in[7];
  const float* Wp1  = (const float*)d_in[8];
  const float* bp1  = (const float*)d_in[9];
  const float* Wp2  = (const float*)d_in[10];
  const float* bp2  = (const float*)d_in[11];
  float* out = (float*)d_out;

  int N = in_sizes[0] / 128;
  int E = in_sizes[1] / 2;
  int nbins = N * SUBK;

  char* ws = (char*)d_ws;
  size_t off = 0;
  float* G1            = (float*)(ws + off); off = alignup(off + (size_t)N*128*sizeof(float));
  unsigned short* XWbf = (unsigned short*)(ws + off); off = alignup(off + (size_t)N*128*sizeof(unsigned short));
  int* csr_src  = (int*)(ws + off); off = alignup(off + (size_t)E*sizeof(int));
  int* slot     = (int*)(ws + off); off = alignup(off + (size_t)E*sizeof(int));
  int* bin_ptr  = (int*)(ws + off); off = alignup(off + (size_t)(nbins+1)*sizeof(int));
  int* cnt      = (int*)(ws + off); off = alignup(off + (size_t)(nbins+4)*sizeof(int));
  int* bsum     = (int*)(ws + off); off = alignup(off + 1024*sizeof(int));
  unsigned short* W1bf = (unsigned short*)(ws + off); off = alignup(off + 128*128*sizeof(unsigned short));
  unsigned short* W2bf = (unsigned short*)(ws + off); off = alignup(off + 128*128*sizeof(unsigned short));
  float* wfold  = (float*)(ws + off); off = alignup(off + 129*sizeof(float));

  const int* esrc = ei;
  const int* edst = ei + E;

  int n4 = (nbins + 3) / 4;
  zero_k<<<(n4 + 255)/256, 256, 0, stream>>>((int4*)cnt, n4);

  int nEB = (E + 255) / 256;
  int nb = (nbins + 1023) / 1024;
  prep_k<<<nEB + 3, 256, 0, stream>>>(edst, cnt, slot, E, nEB,
                                      W1, W1bf, W2, W2bf, Wp1, bp1, Wp2, bp2, wfold);
  scan1_k<<<nb, 1024, 0, stream>>>(cnt, bsum, nbins);
  scan2_k<<<1, 1024, 0, stream>>>(bsum, nb, bin_ptr, nbins, E);
  scan3_k<<<nb, 1024, 0, stream>>>(cnt, bsum, bin_ptr, nbins);
  fill2_k<<<(E+255)/256, 256, 0, stream>>>(esrc, edst, slot, bin_ptr, csr_src, E);

  int gb = (N + 63) / 64;
  // layer 1
  gemm_mfma_k<<<gb, 256, 0, stream>>>(x, W1bf, b1, XWbf, N);
  gat_v5_k<0><<<(N+3)/4, 256, 0, stream>>>(XWbf, att1, bin_ptr, csr_src, G1, nullptr, N);
  // layer 2
  gemm_mfma_k<<<gb, 256, 0, stream>>>(G1, W2bf, b2, XWbf, N);
  gat_v5_k<1><<<(N+3)/4, 256, 0, stream>>>(XWbf, att2, bin_ptr, csr_src, out, wfold, N);
}

// Round 11
// 150.857 us; speedup vs baseline: 1.0844x; 1.0315x over previous
//
#include <hip/hip_runtime.h>
#include <math.h>

typedef __attribute__((ext_vector_type(2))) float f32x2;
typedef __attribute__((ext_vector_type(4))) float fx4;
typedef __attribute__((ext_vector_type(8))) short s16x8;

#define SUBK 8

// ================= zero fill =================

__global__ void zero_k(int4* __restrict__ p, int n4){
  int i = blockIdx.x*blockDim.x + threadIdx.x;
  if(i < n4) p[i] = make_int4(0,0,0,0);
}

// ================= CSR scans / fill =================

__global__ void scan1_k(const int* __restrict__ cnt, int* __restrict__ bsum, int n){
  __shared__ int ws[16];
  int i = blockIdx.x*1024 + threadIdx.x;
  int v = (i < n) ? cnt[i] : 0;
  #pragma unroll
  for(int m=1;m<64;m<<=1) v += __shfl_xor(v, m);
  if((threadIdx.x & 63) == 0) ws[threadIdx.x >> 6] = v;
  __syncthreads();
  if(threadIdx.x == 0){
    int s = 0;
    #pragma unroll
    for(int w=0; w<16; w++) s += ws[w];
    bsum[blockIdx.x] = s;
  }
}

__global__ __launch_bounds__(1024) void scan2_k(int* __restrict__ bsum, int nb,
                                                int* __restrict__ bin_ptr, int nbins, int E){
  __shared__ int sm[1024];
  int t = threadIdx.x;
  int v = (t < nb) ? bsum[t] : 0;
  sm[t] = v;
  __syncthreads();
  for(int off=1; off<1024; off<<=1){
    int tv = (t>=off)? sm[t-off] : 0;
    __syncthreads();
    sm[t] += tv;
    __syncthreads();
  }
  if(t < nb) bsum[t] = sm[t] - v;
  if(t == 0) bin_ptr[nbins] = E;
}

__global__ void scan3_k(const int* __restrict__ cnt, const int* __restrict__ bsum,
                        int* __restrict__ bin_ptr, int n){
  __shared__ int sm[1024];
  int i = blockIdx.x*1024 + threadIdx.x;
  int v = (i<n)? cnt[i] : 0;
  sm[threadIdx.x] = v;
  __syncthreads();
  for(int off=1; off<1024; off<<=1){
    int t = (threadIdx.x>=off)? sm[threadIdx.x-off] : 0;
    __syncthreads();
    sm[threadIdx.x] += t;
    __syncthreads();
  }
  if(i<n)
    bin_ptr[i] = sm[threadIdx.x] - v + bsum[blockIdx.x];
}

__global__ void fill2_k(const int* __restrict__ src, const int* __restrict__ dst,
                        const int* __restrict__ slot, const int* __restrict__ bin_ptr,
                        int* __restrict__ csr_src, int E){
  int e = blockIdx.x*blockDim.x + threadIdx.x;
  if(e < E){
    int bin = dst[e]*SUBK + (e & (SUBK-1));
    csr_src[bin_ptr[bin] + slot[e]] = src[e];
  }
}

// ================= bf16 helpers =================

__device__ __forceinline__ unsigned pack_bf2(float lo, float hi){
  unsigned ul = __float_as_uint(lo); ul += 0x7fffu + ((ul>>16)&1u);
  unsigned uh = __float_as_uint(hi); uh += 0x7fffu + ((uh>>16)&1u);
  return (uh & 0xffff0000u) | (ul >> 16);
}

// ================= shared GEMM core (Wl already staged+swizzled, barrier done) =================
// 64 rows per block tile `brow`; split-hi/lo X for f32-grade accuracy; LDS-coalesced epilogue.

__device__ __forceinline__ void gemm_core(uint4* Wl, const float* __restrict__ X,
    const float* __restrict__ b, unsigned short* __restrict__ Ybf, int nrows, int brow, int t)
{
  int wv = t >> 6, lane = t & 63;
  int r = lane & 15, kb = lane >> 4;
  int row = brow*64 + wv*16 + r;
  const float* xrow = &X[(size_t)min(row, nrows-1)*128];

  fx4 acc[8];
  #pragma unroll
  for(int c=0;c<8;c++) acc[c] = (fx4){0.f,0.f,0.f,0.f};

  #pragma unroll
  for(int kt=0;kt<4;kt++){
    int k0 = kt*32 + kb*8;
    float4 v0 = *(const float4*)&xrow[k0];
    float4 v1 = *(const float4*)&xrow[k0+4];
    float vs[8] = {v0.x,v0.y,v0.z,v0.w,v1.x,v1.y,v1.z,v1.w};
    s16x8 ahi, alo;
    #pragma unroll
    for(int j=0;j<8;j++){
      unsigned u = __float_as_uint(vs[j]);
      unsigned uh = u + 0x7fffu + ((u>>16)&1u);
      unsigned short h = (unsigned short)(uh >> 16);
      float hf = __uint_as_float(((unsigned)h)<<16);
      float lo = vs[j] - hf;
      unsigned ul = __float_as_uint(lo);
      ul += 0x7fffu + ((ul>>16)&1u);
      ahi[j] = (short)h;
      alo[j] = (short)(ul>>16);
    }
    int chunk = kt*4 + kb;
    #pragma unroll
    for(int c=0;c<8;c++){
      uint4 wb = Wl[((c*16 + r)<<4) | (chunk ^ r)];
      s16x8 bb = *(s16x8*)&wb;
      acc[c] = __builtin_amdgcn_mfma_f32_16x16x32_bf16(ahi, bb, acc[c], 0,0,0);
      acc[c] = __builtin_amdgcn_mfma_f32_16x16x32_bf16(alo, bb, acc[c], 0,0,0);
    }
  }

  __syncthreads();                 // all waves done reading W from Wl
  unsigned short* lds = (unsigned short*)Wl;
  unsigned short* my = lds + wv*2048;
  int colb = lane & 15;
  int rq0 = (lane>>4)*4;
  #pragma unroll
  for(int c=0;c<8;c++){
    int col = c*16 + colb;
    float bias = b[col];
    #pragma unroll
    for(int q=0;q<4;q++){
      unsigned u = __float_as_uint(acc[c][q] + bias);
      u += 0x7fffu + ((u>>16)&1u);
      my[(rq0+q)*128 + col] = (unsigned short)(u>>16);
    }
  }
  const uint4* my4 = (const uint4*)my;
  uint4* Y4 = (uint4*)Ybf;
  #pragma unroll
  for(int rr=0;rr<4;rr++){
    int idx = lane + 64*rr;
    int lrow = idx >> 4, lcol = idx & 15;
    int grow = brow*64 + wv*16 + lrow;
    if(grow < nrows)
      Y4[(size_t)grow*16 + lcol] = my4[idx];
  }
}

// ================= merged: gemm1 (W f32 inline-converted) + countslot + W2 conv + fold =================
// gemm blocks first (compute-bound) co-schedule with latency-bound atomic blocks.

__global__ __launch_bounds__(256) void prep_gemm1_k(
    const float* __restrict__ X, const float* __restrict__ W1, const float* __restrict__ b1,
    unsigned short* __restrict__ XWbf, int nrows, int nGB,
    const int* __restrict__ dst, int* __restrict__ cnt, int* __restrict__ slot, int E, int nAB,
    const float* __restrict__ W2, unsigned short* __restrict__ W2bf,
    const float* __restrict__ Wp1, const float* __restrict__ bp1,
    const float* __restrict__ Wp2, const float* __restrict__ bp2,
    float* __restrict__ wfold)
{
  __shared__ uint4 Wl[128*16];
  int b = blockIdx.x;
  int t = threadIdx.x;

  if(b < nGB){
    // ---- gemm1 block: stage W1 (f32) -> bf16 swizzled LDS ----
    #pragma unroll
    for(int i=0;i<8;i++){
      int idx = t + i*256;            // 2048 chunks of 8 bf16
      int row = idx >> 4, ch = idx & 15;
      const float* wsrc = &W1[(size_t)row*128 + ch*8];
      float4 va = *(const float4*)&wsrc[0];
      float4 vb = *(const float4*)&wsrc[4];
      uint4 o;
      o.x = pack_bf2(va.x, va.y); o.y = pack_bf2(va.z, va.w);
      o.z = pack_bf2(vb.x, vb.y); o.w = pack_bf2(vb.z, vb.w);
      Wl[(row<<4) | (ch ^ (row & 15))] = o;
    }
    __syncthreads();
    gemm_core(Wl, X, b1, XWbf, nrows, b, t);
    return;
  }
  int ab = b - nGB;
  if(ab < nAB){
    // ---- atomic block: grid-stride, 4 independent atomic chains in flight ----
    const int STR = nAB*256;
    int base = ab*256 + t;
    int e = base;
    for(; e + 3*STR < E; e += 4*STR){
      int e1 = e+STR, e2 = e+2*STR, e3 = e+3*STR;
      int d0 = dst[e], d1 = dst[e1], d2 = dst[e2], d3 = dst[e3];
      int s0 = atomicAdd(&cnt[d0*SUBK + (e &(SUBK-1))], 1);
      int s1 = atomicAdd(&cnt[d1*SUBK + (e1&(SUBK-1))], 1);
      int s2 = atomicAdd(&cnt[d2*SUBK + (e2&(SUBK-1))], 1);
      int s3 = atomicAdd(&cnt[d3*SUBK + (e3&(SUBK-1))], 1);
      slot[e] = s0; slot[e1] = s1; slot[e2] = s2; slot[e3] = s3;
    }
    for(; e < E; e += STR){
      int d = dst[e];
      slot[e] = atomicAdd(&cnt[d*SUBK + (e&(SUBK-1))], 1);
    }
    return;
  }
  int tb = ab - nAB;
  if(tb == 0){
    // ---- W2 f32 -> bf16 (global, for layer-2 gemm) ----
    const float4* Ws = (const float4*)W2;
    uint2* Wd = (uint2*)W2bf;
    #pragma unroll
    for(int i=0;i<16;i++){
      int idx = t + i*256;
      float4 v = Ws[idx];
      uint2 o; o.x = pack_bf2(v.x, v.y); o.y = pack_bf2(v.z, v.w);
      Wd[idx] = o;
    }
    return;
  }
  // ---- fold block ----
  int k = t;
  if(k < 128){
    float s = 0.f;
    for(int j=0;j<64;j++) s += Wp2[j]*Wp1[(size_t)j*128 + k];
    wfold[k] = s;
  } else if(k == 128){
    float s = bp2[0];
    for(int j=0;j<64;j++) s += Wp2[j]*bp1[j];
    wfold[128] = s;
  }
}

// ================= layer-2 GEMM (W2bf bf16) =================

__global__ __launch_bounds__(256) void gemm_mfma_k(
    const float* __restrict__ X, const unsigned short* __restrict__ Wbf,
    const float* __restrict__ b, unsigned short* __restrict__ Ybf, int nrows)
{
  __shared__ uint4 Wl[128*16];
  int t = threadIdx.x;
  {
    const uint4* Ws = (const uint4*)Wbf;
    #pragma unroll
    for(int i=0;i<8;i++){
      int idx = t + i*256;
      int row = idx >> 4, ch = idx & 15;
      Wl[(row<<4) | (ch ^ (row & 15))] = Ws[idx];
    }
  }
  __syncthreads();
  gemm_core(Wl, X, b, Ybf, nrows, blockIdx.x, t);
}

// ================= GATv2 edge phase v4 (step-4, single prefetch stream) =================

#define BFLO(u) __uint_as_float((u)<<16)
#define BFHI(u) __uint_as_float((u)&0xffff0000u)
#define DPP_ADD(v, ctrl) { int _t = __builtin_amdgcn_update_dpp(0, __float_as_int(v), ctrl, 0xF, 0xF, true); (v) += __int_as_float(_t); }

template<int FUSE>
__global__ __launch_bounds__(256) void gat_v4_k(
    const unsigned short* __restrict__ XWbf,
    const float* __restrict__ att,
    const int* __restrict__ bin_ptr, const int* __restrict__ csr_src,
    float* __restrict__ outp, const float* __restrict__ wfold, int n)
{
  int wid = threadIdx.x >> 6, lane = threadIdx.x & 63;
  int node = blockIdx.x*4 + wid;
  if(node >= n) return;
  int g = lane >> 4;
  int cg = lane & 15;
  int c8 = cg * 8;

  float4 A0 = *(const float4*)&att[c8];
  float4 A1 = *(const float4*)&att[c8+4];
  f32x2 a[4] = { {A0.x,A0.y}, {A0.z,A0.w}, {A1.x,A1.y}, {A1.z,A1.w} };

  const uint4* XW4 = (const uint4*)XWbf;
  uint4 du = XW4[(size_t)node*16 + cg];
  f32x2 xd[4] = { {BFLO(du.x),BFHI(du.x)}, {BFLO(du.y),BFHI(du.y)},
                  {BFLO(du.z),BFHI(du.z)}, {BFLO(du.w),BFHI(du.w)} };

  int beg = bin_ptr[node*SUBK], end = bin_ptr[node*SUBK + SUBK];
  float s = 0.f;
  f32x2 acc[4] = {{0.f,0.f},{0.f,0.f},{0.f,0.f},{0.f,0.f}};

  if(end > beg){
    int sn_cur = csr_src[min(beg + g, end-1)];
    int sn_nxt = (beg+4 < end) ? csr_src[min(beg+4 + g, end-1)] : sn_cur;
    uint4 u = XW4[(size_t)sn_cur*16 + cg];
    for(int i = beg; i < end; i += 4){
      uint4 u_nxt = XW4[(size_t)sn_nxt*16 + cg];
      int sn_nn = (i+8 < end) ? csr_src[min(i+8 + g, end-1)] : sn_nxt;
      bool ok = (i + g) < end;

      f32x2 x0 = {BFLO(u.x), BFHI(u.x)};
      f32x2 x1 = {BFLO(u.y), BFHI(u.y)};
      f32x2 x2 = {BFLO(u.z), BFHI(u.z)};
      f32x2 x3 = {BFLO(u.w), BFHI(u.w)};
      f32x2 v0 = xd[0]+x0, v1 = xd[1]+x1, v2 = xd[2]+x2, v3 = xd[3]+x3;
      f32x2 q0 = v0*0.2f, q1 = v1*0.2f, q2 = v2*0.2f, q3 = v3*0.2f;
      f32x2 l0, l1, l2, l3;
      l0.x = fmaxf(v0.x,q0.x); l0.y = fmaxf(v0.y,q0.y);
      l1.x = fmaxf(v1.x,q1.x); l1.y = fmaxf(v1.y,q1.y);
      l2.x = fmaxf(v2.x,q2.x); l2.y = fmaxf(v2.y,q2.y);
      l3.x = fmaxf(v3.x,q3.x); l3.y = fmaxf(v3.y,q3.y);
      f32x2 p2 = l0*a[0];
      p2 += l1*a[1];
      p2 += l2*a[2];
      p2 += l3*a[3];
      float p = p2.x + p2.y;
      DPP_ADD(p, 0xB1);
      DPP_ADD(p, 0x4E);
      DPP_ADD(p, 0x141);
      float ex = ok ? __expf(fminf(p, 60.f)) : 0.f;
      s += ex;
      f32x2 e2 = {ex, ex};
      acc[0] += e2*x0;
      acc[1] += e2*x1;
      acc[2] += e2*x2;
      acc[3] += e2*x3;

      u = u_nxt; sn_nxt = sn_nn;
    }
  }

  s += __shfl_xor(s,16);  s += __shfl_xor(s,32);
  #pragma unroll
  for(int j=0;j<4;j++){
    acc[j].x += __shfl_xor(acc[j].x,16); acc[j].x += __shfl_xor(acc[j].x,32);
    acc[j].y += __shfl_xor(acc[j].y,16); acc[j].y += __shfl_xor(acc[j].y,32);
  }

  float inv = (s > 0.f) ? 1.f/s : 0.f;
  f32x2 o[4];
  #pragma unroll
  for(int j=0;j<4;j++){
    o[j].x = fmaxf(acc[j].x*inv, 0.f);
    o[j].y = fmaxf(acc[j].y*inv, 0.f);
  }

  if(FUSE == 0){
    if(lane < 16){
      *(float4*)&outp[(size_t)node*128 + c8]     = make_float4(o[0].x,o[0].y,o[1].x,o[1].y);
      *(float4*)&outp[(size_t)node*128 + c8 + 4] = make_float4(o[2].x,o[2].y,o[3].x,o[3].y);
    }
  } else {
    float4 wf0 = *(const float4*)&wfold[c8];
    float4 wf1 = *(const float4*)&wfold[c8+4];
    float tt = o[0].x*wf0.x + o[0].y*wf0.y + o[1].x*wf0.z + o[1].y*wf0.w
             + o[2].x*wf1.x + o[2].y*wf1.y + o[3].x*wf1.z + o[3].y*wf1.w;
    DPP_ADD(tt, 0xB1);
    DPP_ADD(tt, 0x4E);
    DPP_ADD(tt, 0x141);
    DPP_ADD(tt, 0x140);
    if(lane == 0)
      outp[node] = 1.f/(1.f + __expf(-(tt + wfold[128])));
  }
}

// ================= launcher =================

static inline size_t alignup(size_t v){ return (v + 255) & ~(size_t)255; }

extern "C" void kernel_launch(void* const* d_in, const int* in_sizes, int n_in,
                              void* d_out, int out_size, void* d_ws, size_t ws_size,
                              hipStream_t stream) {
  const float* x    = (const float*)d_in[0];
  const int*   ei   = (const int*)  d_in[1];
  const float* W1   = (const float*)d_in[2];
  const float* b1   = (const float*)d_in[3];
  const float* att1 = (const float*)d_in[4];
  const float* W2   = (const float*)d_in[5];
  const float* b2   = (const float*)d_in[6];
  const float* att2 = (const float*)d_in[7];
  const float* Wp1  = (const float*)d_in[8];
  const float* bp1  = (const float*)d_in[9];
  const float* Wp2  = (const float*)d_in[10];
  const float* bp2  = (const float*)d_in[11];
  float* out = (float*)d_out;

  int N = in_sizes[0] / 128;
  int E = in_sizes[1] / 2;
  int nbins = N * SUBK;

  char* ws = (char*)d_ws;
  size_t off = 0;
  float* G1            = (float*)(ws + off); off = alignup(off + (size_t)N*128*sizeof(float));
  unsigned short* XWbf = (unsigned short*)(ws + off); off = alignup(off + (size_t)N*128*sizeof(unsigned short));
  int* csr_src  = (int*)(ws + off); off = alignup(off + (size_t)E*sizeof(int));
  int* slot     = (int*)(ws + off); off = alignup(off + (size_t)E*sizeof(int));
  int* bin_ptr  = (int*)(ws + off); off = alignup(off + (size_t)(nbins+1)*sizeof(int));
  int* cnt      = (int*)(ws + off); off = alignup(off + (size_t)(nbins+4)*sizeof(int));
  int* bsum     = (int*)(ws + off); off = alignup(off + 1024*sizeof(int));
  unsigned short* W2bf = (unsigned short*)(ws + off); off = alignup(off + 128*128*sizeof(unsigned short));
  float* wfold  = (float*)(ws + off); off = alignup(off + 129*sizeof(float));

  const int* esrc = ei;
  const int* edst = ei + E;

  int n4 = (nbins + 3) / 4;
  zero_k<<<(n4 + 255)/256, 256, 0, stream>>>((int4*)cnt, n4);

  int nGB = (N + 63) / 64;
  int nAB = 256;
  int nb = (nbins + 1023) / 1024;

  // merged: gemm1 + countslot + W2 convert + fold (independent work co-scheduled)
  prep_gemm1_k<<<nGB + nAB + 2, 256, 0, stream>>>(
      x, W1, b1, XWbf, N, nGB,
      edst, cnt, slot, E, nAB,
      W2, W2bf, Wp1, bp1, Wp2, bp2, wfold);

  scan1_k<<<nb, 1024, 0, stream>>>(cnt, bsum, nbins);
  scan2_k<<<1, 1024, 0, stream>>>(bsum, nb, bin_ptr, nbins, E);
  scan3_k<<<nb, 1024, 0, stream>>>(cnt, bsum, bin_ptr, nbins);
  fill2_k<<<(E+255)/256, 256, 0, stream>>>(esrc, edst, slot, bin_ptr, csr_src, E);

  // layer 1 edge phase
  gat_v4_k<0><<<(N+3)/4, 256, 0, stream>>>(XWbf, att1, bin_ptr, csr_src, G1, nullptr, N);
  // layer 2
  gemm_mfma_k<<<nGB, 256, 0, stream>>>(G1, W2bf, b2, XWbf, N);
  gat_v4_k<1><<<(N+3)/4, 256, 0, stream>>>(XWbf, att2, bin_ptr, csr_src, out, wfold, N);
}